// Round 5
// baseline (450.638 us; speedup 1.0000x reference)
//
#include <hip/hip_runtime.h>
#include <hip/hip_bf16.h>
#include <cstdint>

#define N_NODES 100000
#define BQ      20000
#define KN      32
#define DIM     256
#define NEGV    -1000000.0f

typedef float          f32x4 __attribute__((ext_vector_type(4)));
typedef __bf16         bfx4  __attribute__((ext_vector_type(4)));
typedef __bf16         bfx8  __attribute__((ext_vector_type(8)));
typedef unsigned short u16x8 __attribute__((ext_vector_type(8)));
typedef unsigned short u16x4 __attribute__((ext_vector_type(4)));

// ---------------------------------------------------------------------------
// Kernel 1: proj = leaky_relu(word_vec @ W1^T)  [N,256] fp32 out
// 128x128 output tile per block, K staged in 4 steps of BK=64 (32 KiB LDS,
// XOR-swizzled bf16), native casts -> v_cvt_pk_bf16_f32, 4 waves x 64x64 quad.
// ---------------------------------------------------------------------------
__global__ __launch_bounds__(256) void proj_gemm(const float* __restrict__ A,
                                                 const float* __restrict__ W,
                                                 float* __restrict__ out) {
    __shared__ unsigned short As[128 * 64];  // 16 KiB bf16, swizzled (row stride 128B)
    __shared__ unsigned short Bs[128 * 64];  // 16 KiB

    const int tile = blockIdx.x;
    const int mt = tile >> 1, nt = tile & 1;
    const int m0 = mt * 128, n0 = nt * 128;
    const int t = threadIdx.x;
    const int lane = t & 63;
    const int w = t >> 6;
    const int wm = (w >> 1) * 64;   // wave's M offset in tile
    const int wn = (w & 1) * 64;    // wave's N offset in tile

    f32x4 acc[4][4];
#pragma unroll
    for (int i = 0; i < 4; ++i)
#pragma unroll
        for (int j = 0; j < 4; ++j) acc[i][j] = f32x4{0.f, 0.f, 0.f, 0.f};

#pragma unroll 1
    for (int kk = 0; kk < 4; ++kk) {
        const int k0 = kk * 64;

        // ---- stage A and B: 128 rows x 64 cols each, fp32 -> bf16 ----
        // slot = it*256 + t ; row = slot>>4 (16 f32x4-chunks per row), chunk = slot&15
#pragma unroll
        for (int it = 0; it < 8; ++it) {
            const int slot = it * 256 + t;
            const int row = slot >> 4;
            const int colf = (slot & 15) * 4;          // f32 col within BK
            const int byte = (row * 128 + colf * 2) ^ ((row & 7) << 4);
            // A
            {
                const int gr = m0 + row;
                f32x4 v = f32x4{0.f, 0.f, 0.f, 0.f};
                if (gr < N_NODES) v = *(const f32x4*)&A[(size_t)gr * 256 + k0 + colf];
                bfx4 h = {(__bf16)v[0], (__bf16)v[1], (__bf16)v[2], (__bf16)v[3]};
                *reinterpret_cast<bfx4*>(reinterpret_cast<char*>(As) + byte) = h;
            }
            // B (W1 rows n0+row <= 255, always valid)
            {
                const int gr = n0 + row;
                f32x4 v = *(const f32x4*)&W[(size_t)gr * 256 + k0 + colf];
                bfx4 h = {(__bf16)v[0], (__bf16)v[1], (__bf16)v[2], (__bf16)v[3]};
                *reinterpret_cast<bfx4*>(reinterpret_cast<char*>(Bs) + byte) = h;
            }
        }
        __syncthreads();

        // ---- MFMA over this K-step: 2 sub-steps of K=32 ----
#pragma unroll
        for (int ks = 0; ks < 2; ++ks) {
            const int colb = ks * 64 + ((lane >> 4) * 16);  // byte col in 128B LDS row
            bfx8 af[4], bfv[4];
#pragma unroll
            for (int mi = 0; mi < 4; ++mi) {
                const int row = wm + mi * 16 + (lane & 15);
                const int byte = row * 128 + (colb ^ ((row & 7) << 4));
                af[mi] = __builtin_bit_cast(
                    bfx8, *reinterpret_cast<const u16x8*>(reinterpret_cast<const char*>(As) + byte));
            }
#pragma unroll
            for (int ni = 0; ni < 4; ++ni) {
                const int row = wn + ni * 16 + (lane & 15);
                const int byte = row * 128 + (colb ^ ((row & 7) << 4));
                bfv[ni] = __builtin_bit_cast(
                    bfx8, *reinterpret_cast<const u16x8*>(reinterpret_cast<const char*>(Bs) + byte));
            }
#pragma unroll
            for (int mi = 0; mi < 4; ++mi)
#pragma unroll
                for (int ni = 0; ni < 4; ++ni)
                    acc[mi][ni] = __builtin_amdgcn_mfma_f32_16x16x32_bf16(af[mi], bfv[ni],
                                                                          acc[mi][ni], 0, 0, 0);
        }
        __syncthreads();
    }

    // ---- epilogue: leaky_relu + store ----
    const int cr = (lane >> 4) * 4;  // fragment row base
    const int cc = lane & 15;        // fragment col
#pragma unroll
    for (int mi = 0; mi < 4; ++mi) {
#pragma unroll
        for (int r = 0; r < 4; ++r) {
            const int grow = m0 + wm + mi * 16 + cr + r;
            if (grow < N_NODES) {
#pragma unroll
                for (int ni = 0; ni < 4; ++ni) {
                    float v = acc[mi][ni][r];
                    v = v > 0.f ? v : 0.2f * v;
                    out[(size_t)grow * 256 + n0 + wn + ni * 16 + cc] = v;
                }
            }
        }
    }
}

// ---------------------------------------------------------------------------
// Kernel 2: per-b scores + masked softmaxes + weighted aggregation.
// One block / b. Wave w owns neighbors 8w..8w+7.
//  - score phase: preload 8 full wv rows into regs (f32x4/lane), then reduce
//  - agg-phase loads issued BEFORE softmax barrier (dep only on nsh)
//  - agg phase: wave reads full 1KB rows; partials combined via LDS
// ---------------------------------------------------------------------------
__global__ __launch_bounds__(256) void att_agg(const float* __restrict__ wv,
                                               const float* __restrict__ Waux,
                                               const float* __restrict__ aux,
                                               const int* __restrict__ src_idx,
                                               const int* __restrict__ nidx,
                                               const int* __restrict__ smask,
                                               const float* __restrict__ proj,
                                               float* __restrict__ agg) {
    __shared__ int   nsh[32];
    __shared__ int   msh[32];
    __shared__ float sc[32];
    __shared__ float sa[32];
    __shared__ float wsh[32];
    __shared__ float part[4][64][4];   // 4 KiB wave partials

    const int b = blockIdx.x;
    const int t = threadIdx.x;
    const int lane = t & 63;
    const int w = t >> 6;
    const int src = src_idx[b];

    if (t < 32) {
        nsh[t] = nidx[b * KN + t];
        msh[t] = smask[b * KN + t];
        f32x4 a4 = *(const f32x4*)&aux[((size_t)b * KN + t) * 4];
        const float x = a4[0] * Waux[0] + a4[1] * Waux[1] + a4[2] * Waux[2] + a4[3] * Waux[3];
        sa[t] = 1.f / (1.f + expf(-x));
    }
    // q fragment (each wave loads the same 1KB row; L2-hot, no barrier needed)
    const f32x4 q4 = *(const f32x4*)&wv[(size_t)src * 256 + lane * 4];
    __syncthreads();   // nsh/msh/sa visible

    int nk[8];
#pragma unroll
    for (int i = 0; i < 8; ++i) nk[i] = nsh[w * 8 + i];

    // preload 8 score rows (wv) AND 8 agg rows (proj): 16 independent loads
    f32x4 k4[8], v4[8];
#pragma unroll
    for (int i = 0; i < 8; ++i)
        k4[i] = *(const f32x4*)&wv[(size_t)nk[i] * 256 + lane * 4];
#pragma unroll
    for (int i = 0; i < 8; ++i)
        v4[i] = *(const f32x4*)&proj[(size_t)nk[i] * 256 + lane * 4];

    // scores: full-wave 256-dim dots
#pragma unroll
    for (int i = 0; i < 8; ++i) {
        float p = q4[0] * k4[i][0] + q4[1] * k4[i][1] + q4[2] * k4[i][2] + q4[3] * k4[i][3];
#pragma unroll
        for (int o = 32; o > 0; o >>= 1) p += __shfl_xor(p, o);
        if (lane == 0) sc[w * 8 + i] = 5.f * p;
    }
    __syncthreads();

    // masked dual softmax over K=32 (lanes 0..31 of wave 0)
    if (t < 32) {
        const bool mk = (msh[t] == 1);
        const float s1 = mk ? sc[t] : NEGV;
        const float s2 = mk ? sa[t] : NEGV;
        float m1 = s1, m2 = s2;
#pragma unroll
        for (int o = 16; o > 0; o >>= 1) {
            m1 = fmaxf(m1, __shfl_xor(m1, o));
            m2 = fmaxf(m2, __shfl_xor(m2, o));
        }
        const float e1 = expf(s1 - m1), e2 = expf(s2 - m2);
        float z1 = e1, z2 = e2;
#pragma unroll
        for (int o = 16; o > 0; o >>= 1) {
            z1 += __shfl_xor(z1, o);
            z2 += __shfl_xor(z2, o);
        }
        wsh[t] = 0.5f * (e1 / z1 + e2 / z2);
    }
    __syncthreads();

    // weighted partial sum over this wave's 8 neighbors (v4 already in regs)
    f32x4 pacc = f32x4{0.f, 0.f, 0.f, 0.f};
#pragma unroll
    for (int i = 0; i < 8; ++i) {
        const float wk = wsh[w * 8 + i];
#pragma unroll
        for (int j = 0; j < 4; ++j) pacc[j] += wk * v4[i][j];
    }
    *(f32x4*)&part[w][lane][0] = pacc;
    __syncthreads();

    if (w == 0) {
        f32x4 s0 = *(const f32x4*)&part[0][lane][0];
        f32x4 s1 = *(const f32x4*)&part[1][lane][0];
        f32x4 s2 = *(const f32x4*)&part[2][lane][0];
        f32x4 s3 = *(const f32x4*)&part[3][lane][0];
        f32x4 s;
#pragma unroll
        for (int j = 0; j < 4; ++j) s[j] = (s0[j] + s1[j]) + (s2[j] + s3[j]);
        *(f32x4*)&agg[(size_t)b * 256 + lane * 4] = s;
    }
}

// ---------------------------------------------------------------------------
// Kernel 3: scatter agg rows into out at src_idx
// ---------------------------------------------------------------------------
__global__ __launch_bounds__(256) void scatter_agg(const int* __restrict__ src_idx,
                                                   const float* __restrict__ agg,
                                                   float* __restrict__ out) {
    const int b = blockIdx.x;
    const int t = threadIdx.x;
    out[(size_t)src_idx[b] * 256 + t] = agg[(size_t)b * 256 + t];
}

extern "C" void kernel_launch(void* const* d_in, const int* in_sizes, int n_in,
                              void* d_out, int out_size, void* d_ws, size_t ws_size,
                              hipStream_t stream) {
    const float* wv   = (const float*)d_in[0];  // word_vec [N,256]
    const float* W1   = (const float*)d_in[1];  // [256,256]
    const float* Waux = (const float*)d_in[2];  // [1,4]
    const float* aux  = (const float*)d_in[3];  // [B,K,4]
    const int*   src  = (const int*)d_in[4];    // [B]
    const int*   nidx = (const int*)d_in[5];    // [B,K]
    const int*   smk  = (const int*)d_in[6];    // [B,K]
    float* out = (float*)d_out;                 // [N,256]
    float* agg = (float*)d_ws;                  // [B,256] scratch (20.48 MB)

    const int mtiles = (N_NODES + 127) / 128;   // 782
    proj_gemm<<<dim3(mtiles * 2), dim3(256), 0, stream>>>(wv, W1, out);
    att_agg<<<dim3(BQ), dim3(256), 0, stream>>>(wv, Waux, aux, src, nidx, smk, out, agg);
    scatter_agg<<<dim3(BQ), dim3(256), 0, stream>>>(src, agg, out);
}

// Round 6
// 390.628 us; speedup vs baseline: 1.1536x; 1.1536x over previous
//
#include <hip/hip_runtime.h>
#include <hip/hip_bf16.h>
#include <cstdint>

#define N_NODES 100000
#define BQ      20000
#define KN      32
#define NEGV    -1000000.0f

typedef float          f32x4 __attribute__((ext_vector_type(4)));
typedef __bf16         bfx4  __attribute__((ext_vector_type(4)));
typedef __bf16         bfx8  __attribute__((ext_vector_type(8)));
typedef _Float16       h16x4 __attribute__((ext_vector_type(4)));
typedef unsigned short u16x8 __attribute__((ext_vector_type(8)));

// ---------------------------------------------------------------------------
// Kernel 1: proj = leaky_relu(word_vec @ W1^T) -> out (fp32)
// If W16: also emit wv16 (f16 copy of word_vec, from A-staging, nt==0 blocks)
// and proj16 (f16 copy of proj, from epilogue) into workspace.
// 128x128 tile, BK=64, XOR-swizzled bf16 LDS, 4 waves x 64x64 quadrant.
// Grid must be 1564 blocks (bijective XCD swizzle constants assume it).
// ---------------------------------------------------------------------------
template <bool W16>
__global__ __launch_bounds__(256) void proj_gemm(const float* __restrict__ A,
                                                 const float* __restrict__ W,
                                                 float* __restrict__ out,
                                                 _Float16* __restrict__ wv16,
                                                 _Float16* __restrict__ pj16) {
    __shared__ unsigned short As[128 * 64];  // 16 KiB bf16, swizzled (row stride 128B)
    __shared__ unsigned short Bs[128 * 64];  // 16 KiB

    // bijective XCD swizzle for nwg=1564: q=195, r=4 (m204 formula)
    const int bid = blockIdx.x;
    const int xcd = bid & 7, idx = bid >> 3;
    const int tile = (xcd < 4 ? xcd * 196 : 784 + (xcd - 4) * 195) + idx;

    const int mt = tile >> 1, nt = tile & 1;
    const int m0 = mt * 128, n0 = nt * 128;
    const int t = threadIdx.x;
    const int lane = t & 63;
    const int w = t >> 6;
    const int wm = (w >> 1) * 64;
    const int wn = (w & 1) * 64;

    f32x4 acc[4][4];
#pragma unroll
    for (int i = 0; i < 4; ++i)
#pragma unroll
        for (int j = 0; j < 4; ++j) acc[i][j] = f32x4{0.f, 0.f, 0.f, 0.f};

#pragma unroll 1
    for (int kk = 0; kk < 4; ++kk) {
        const int k0 = kk * 64;

        // ---- stage A and B: 128 rows x 64 cols, fp32 -> bf16 (+f16 side-write) ----
#pragma unroll
        for (int it = 0; it < 8; ++it) {
            const int slot = it * 256 + t;
            const int row = slot >> 4;
            const int colf = (slot & 15) * 4;
            const int byte = (row * 128 + colf * 2) ^ ((row & 7) << 4);
            // A
            {
                const int gr = m0 + row;
                f32x4 v = f32x4{0.f, 0.f, 0.f, 0.f};
                if (gr < N_NODES) v = *(const f32x4*)&A[(size_t)gr * 256 + k0 + colf];
                bfx4 h = {(__bf16)v[0], (__bf16)v[1], (__bf16)v[2], (__bf16)v[3]};
                *reinterpret_cast<bfx4*>(reinterpret_cast<char*>(As) + byte) = h;
                if constexpr (W16) {
                    if (nt == 0 && gr < N_NODES) {
                        h16x4 hh = {(_Float16)v[0], (_Float16)v[1], (_Float16)v[2],
                                    (_Float16)v[3]};
                        *(h16x4*)&wv16[(size_t)gr * 256 + k0 + colf] = hh;
                    }
                }
            }
            // B (W1 rows n0+row <= 255, always valid)
            {
                const int gr = n0 + row;
                f32x4 v = *(const f32x4*)&W[(size_t)gr * 256 + k0 + colf];
                bfx4 h = {(__bf16)v[0], (__bf16)v[1], (__bf16)v[2], (__bf16)v[3]};
                *reinterpret_cast<bfx4*>(reinterpret_cast<char*>(Bs) + byte) = h;
            }
        }
        __syncthreads();

        // ---- MFMA: 2 sub-steps of K=32 ----
#pragma unroll
        for (int ks = 0; ks < 2; ++ks) {
            const int colb = ks * 64 + ((lane >> 4) * 16);
            bfx8 af[4], bfv[4];
#pragma unroll
            for (int mi = 0; mi < 4; ++mi) {
                const int row = wm + mi * 16 + (lane & 15);
                const int byte = row * 128 + (colb ^ ((row & 7) << 4));
                af[mi] = __builtin_bit_cast(
                    bfx8, *reinterpret_cast<const u16x8*>(reinterpret_cast<const char*>(As) + byte));
            }
#pragma unroll
            for (int ni = 0; ni < 4; ++ni) {
                const int row = wn + ni * 16 + (lane & 15);
                const int byte = row * 128 + (colb ^ ((row & 7) << 4));
                bfv[ni] = __builtin_bit_cast(
                    bfx8, *reinterpret_cast<const u16x8*>(reinterpret_cast<const char*>(Bs) + byte));
            }
#pragma unroll
            for (int mi = 0; mi < 4; ++mi)
#pragma unroll
                for (int ni = 0; ni < 4; ++ni)
                    acc[mi][ni] = __builtin_amdgcn_mfma_f32_16x16x32_bf16(af[mi], bfv[ni],
                                                                          acc[mi][ni], 0, 0, 0);
        }
        __syncthreads();
    }

    // ---- epilogue: leaky_relu + fp32 store (+ f16 side-store) ----
    const int cr = (lane >> 4) * 4;
    const int cc = lane & 15;
#pragma unroll
    for (int mi = 0; mi < 4; ++mi) {
#pragma unroll
        for (int r = 0; r < 4; ++r) {
            const int grow = m0 + wm + mi * 16 + cr + r;
            if (grow < N_NODES) {
#pragma unroll
                for (int ni = 0; ni < 4; ++ni) {
                    float v = acc[mi][ni][r];
                    v = v > 0.f ? v : 0.2f * v;
                    const size_t o = (size_t)grow * 256 + n0 + wn + ni * 16 + cc;
                    out[o] = v;
                    if constexpr (W16) pj16[o] = (_Float16)v;
                }
            }
        }
    }
}

// ---------------------------------------------------------------------------
// Kernel 2 (fast path): gathers from f16 copies; writes agg directly to out.
// One block / b; wave w owns neighbors 8w..8w+7. q stays fp32 (exact scores up
// to the k-side f16 rounding).
// ---------------------------------------------------------------------------
__global__ __launch_bounds__(256) void att_agg16(const float* __restrict__ wv,
                                                 const _Float16* __restrict__ wv16,
                                                 const _Float16* __restrict__ pj16,
                                                 const float* __restrict__ Waux,
                                                 const float* __restrict__ aux,
                                                 const int* __restrict__ src_idx,
                                                 const int* __restrict__ nidx,
                                                 const int* __restrict__ smask,
                                                 float* __restrict__ out) {
    __shared__ int   nsh[32];
    __shared__ int   msh[32];
    __shared__ float sc[32];
    __shared__ float sa[32];
    __shared__ float wsh[32];
    __shared__ float part[4][64][4];

    const int b = blockIdx.x;
    const int t = threadIdx.x;
    const int lane = t & 63;
    const int w = t >> 6;
    const int src = src_idx[b];

    if (t < 32) {
        nsh[t] = nidx[b * KN + t];
        msh[t] = smask[b * KN + t];
        f32x4 a4 = *(const f32x4*)&aux[((size_t)b * KN + t) * 4];
        const float x = a4[0] * Waux[0] + a4[1] * Waux[1] + a4[2] * Waux[2] + a4[3] * Waux[3];
        sa[t] = 1.f / (1.f + expf(-x));
    }
    const f32x4 q4 = *(const f32x4*)&wv[(size_t)src * 256 + lane * 4];
    __syncthreads();

    int nk[8];
#pragma unroll
    for (int i = 0; i < 8; ++i) nk[i] = nsh[w * 8 + i];

    // preload 8 f16 score rows + 8 f16 agg rows (8B/lane each)
    h16x4 k4[8], v4[8];
#pragma unroll
    for (int i = 0; i < 8; ++i)
        k4[i] = *(const h16x4*)&wv16[(size_t)nk[i] * 256 + lane * 4];
#pragma unroll
    for (int i = 0; i < 8; ++i)
        v4[i] = *(const h16x4*)&pj16[(size_t)nk[i] * 256 + lane * 4];

    // scores: full-wave 256-dim dots
#pragma unroll
    for (int i = 0; i < 8; ++i) {
        float p = q4[0] * (float)k4[i][0] + q4[1] * (float)k4[i][1] +
                  q4[2] * (float)k4[i][2] + q4[3] * (float)k4[i][3];
#pragma unroll
        for (int o = 32; o > 0; o >>= 1) p += __shfl_xor(p, o);
        if (lane == 0) sc[w * 8 + i] = 5.f * p;
    }
    __syncthreads();

    // masked dual softmax over K=32 (lanes 0..31 of wave 0)
    if (t < 32) {
        const bool mk = (msh[t] == 1);
        const float s1 = mk ? sc[t] : NEGV;
        const float s2 = mk ? sa[t] : NEGV;
        float m1 = s1, m2 = s2;
#pragma unroll
        for (int o = 16; o > 0; o >>= 1) {
            m1 = fmaxf(m1, __shfl_xor(m1, o));
            m2 = fmaxf(m2, __shfl_xor(m2, o));
        }
        const float e1 = expf(s1 - m1), e2 = expf(s2 - m2);
        float z1 = e1, z2 = e2;
#pragma unroll
        for (int o = 16; o > 0; o >>= 1) {
            z1 += __shfl_xor(z1, o);
            z2 += __shfl_xor(z2, o);
        }
        wsh[t] = 0.5f * (e1 / z1 + e2 / z2);
    }
    __syncthreads();

    // weighted partial sum (v4 already in regs)
    f32x4 pacc = f32x4{0.f, 0.f, 0.f, 0.f};
#pragma unroll
    for (int i = 0; i < 8; ++i) {
        const float wk = wsh[w * 8 + i];
#pragma unroll
        for (int j = 0; j < 4; ++j) pacc[j] += wk * (float)v4[i][j];
    }
    *(f32x4*)&part[w][lane][0] = pacc;
    __syncthreads();

    if (w == 0) {
        f32x4 s0 = *(const f32x4*)&part[0][lane][0];
        f32x4 s1 = *(const f32x4*)&part[1][lane][0];
        f32x4 s2 = *(const f32x4*)&part[2][lane][0];
        f32x4 s3 = *(const f32x4*)&part[3][lane][0];
        f32x4 s;
#pragma unroll
        for (int j = 0; j < 4; ++j) s[j] = (s0[j] + s1[j]) + (s2[j] + s3[j]);
        *(f32x4*)&out[(size_t)src * 256 + lane * 4] = s;  // fused scatter
    }
}

// ---------------------------------------------------------------------------
// Fallback path (ws too small): fp32 gathers from out + separate scatter.
// ---------------------------------------------------------------------------
__global__ __launch_bounds__(256) void att_agg_f32(const float* __restrict__ wv,
                                                   const float* __restrict__ Waux,
                                                   const float* __restrict__ aux,
                                                   const int* __restrict__ src_idx,
                                                   const int* __restrict__ nidx,
                                                   const int* __restrict__ smask,
                                                   const float* __restrict__ proj,
                                                   float* __restrict__ agg) {
    __shared__ int   nsh[32];
    __shared__ int   msh[32];
    __shared__ float sc[32];
    __shared__ float sa[32];
    __shared__ float wsh[32];
    __shared__ float part[4][64][4];

    const int b = blockIdx.x;
    const int t = threadIdx.x;
    const int lane = t & 63;
    const int w = t >> 6;
    const int src = src_idx[b];

    if (t < 32) {
        nsh[t] = nidx[b * KN + t];
        msh[t] = smask[b * KN + t];
        f32x4 a4 = *(const f32x4*)&aux[((size_t)b * KN + t) * 4];
        const float x = a4[0] * Waux[0] + a4[1] * Waux[1] + a4[2] * Waux[2] + a4[3] * Waux[3];
        sa[t] = 1.f / (1.f + expf(-x));
    }
    const f32x4 q4 = *(const f32x4*)&wv[(size_t)src * 256 + lane * 4];
    __syncthreads();

    int nk[8];
#pragma unroll
    for (int i = 0; i < 8; ++i) nk[i] = nsh[w * 8 + i];
    f32x4 k4[8], v4[8];
#pragma unroll
    for (int i = 0; i < 8; ++i) k4[i] = *(const f32x4*)&wv[(size_t)nk[i] * 256 + lane * 4];
#pragma unroll
    for (int i = 0; i < 8; ++i) v4[i] = *(const f32x4*)&proj[(size_t)nk[i] * 256 + lane * 4];

#pragma unroll
    for (int i = 0; i < 8; ++i) {
        float p = q4[0] * k4[i][0] + q4[1] * k4[i][1] + q4[2] * k4[i][2] + q4[3] * k4[i][3];
#pragma unroll
        for (int o = 32; o > 0; o >>= 1) p += __shfl_xor(p, o);
        if (lane == 0) sc[w * 8 + i] = 5.f * p;
    }
    __syncthreads();

    if (t < 32) {
        const bool mk = (msh[t] == 1);
        const float s1 = mk ? sc[t] : NEGV;
        const float s2 = mk ? sa[t] : NEGV;
        float m1 = s1, m2 = s2;
#pragma unroll
        for (int o = 16; o > 0; o >>= 1) {
            m1 = fmaxf(m1, __shfl_xor(m1, o));
            m2 = fmaxf(m2, __shfl_xor(m2, o));
        }
        const float e1 = expf(s1 - m1), e2 = expf(s2 - m2);
        float z1 = e1, z2 = e2;
#pragma unroll
        for (int o = 16; o > 0; o >>= 1) {
            z1 += __shfl_xor(z1, o);
            z2 += __shfl_xor(z2, o);
        }
        wsh[t] = 0.5f * (e1 / z1 + e2 / z2);
    }
    __syncthreads();

    f32x4 pacc = f32x4{0.f, 0.f, 0.f, 0.f};
#pragma unroll
    for (int i = 0; i < 8; ++i) {
        const float wk = wsh[w * 8 + i];
#pragma unroll
        for (int j = 0; j < 4; ++j) pacc[j] += wk * v4[i][j];
    }
    *(f32x4*)&part[w][lane][0] = pacc;
    __syncthreads();

    if (w == 0) {
        f32x4 s0 = *(const f32x4*)&part[0][lane][0];
        f32x4 s1 = *(const f32x4*)&part[1][lane][0];
        f32x4 s2 = *(const f32x4*)&part[2][lane][0];
        f32x4 s3 = *(const f32x4*)&part[3][lane][0];
        f32x4 s;
#pragma unroll
        for (int j = 0; j < 4; ++j) s[j] = (s0[j] + s1[j]) + (s2[j] + s3[j]);
        *(f32x4*)&agg[(size_t)b * 256 + lane * 4] = s;
    }
}

__global__ __launch_bounds__(256) void scatter_agg(const int* __restrict__ src_idx,
                                                   const float* __restrict__ agg,
                                                   float* __restrict__ out) {
    const int b = blockIdx.x;
    const int t = threadIdx.x;
    out[(size_t)src_idx[b] * 256 + t] = agg[(size_t)b * 256 + t];
}

extern "C" void kernel_launch(void* const* d_in, const int* in_sizes, int n_in,
                              void* d_out, int out_size, void* d_ws, size_t ws_size,
                              hipStream_t stream) {
    const float* wv   = (const float*)d_in[0];  // word_vec [N,256]
    const float* W1   = (const float*)d_in[1];  // [256,256]
    const float* Waux = (const float*)d_in[2];  // [1,4]
    const float* aux  = (const float*)d_in[3];  // [B,K,4]
    const int*   src  = (const int*)d_in[4];    // [B]
    const int*   nidx = (const int*)d_in[5];    // [B,K]
    const int*   smk  = (const int*)d_in[6];    // [B,K]
    float* out = (float*)d_out;                 // [N,256]

    const int mtiles = (N_NODES + 127) / 128;   // 782 -> grid 1564 (swizzle constants)
    const size_t elems = (size_t)N_NODES * 256;
    const size_t need = elems * 2 * sizeof(_Float16);  // wv16 + proj16 = 102.4 MB

    if (ws_size >= need) {
        _Float16* wv16 = (_Float16*)d_ws;
        _Float16* pj16 = wv16 + elems;
        proj_gemm<true><<<dim3(mtiles * 2), dim3(256), 0, stream>>>(wv, W1, out, wv16, pj16);
        att_agg16<<<dim3(BQ), dim3(256), 0, stream>>>(wv, wv16, pj16, Waux, aux, src, nidx,
                                                      smk, out);
    } else {
        float* agg = (float*)d_ws;  // [B,256]
        proj_gemm<false><<<dim3(mtiles * 2), dim3(256), 0, stream>>>(wv, W1, out, nullptr,
                                                                     nullptr);
        att_agg_f32<<<dim3(BQ), dim3(256), 0, stream>>>(wv, Waux, aux, src, nidx, smk, out,
                                                        agg);
        scatter_agg<<<dim3(BQ), dim3(256), 0, stream>>>(src, agg, out);
    }
}

// Round 9
// 362.859 us; speedup vs baseline: 1.2419x; 1.0765x over previous
//
#include <hip/hip_runtime.h>
#include <cstdint>

#define N_NODES 100000
#define BQ      20000
#define KN      32
#define NEGV    -1000000.0f

typedef float    f32x4 __attribute__((ext_vector_type(4)));
typedef _Float16 h16x4 __attribute__((ext_vector_type(4)));
typedef _Float16 h16x8 __attribute__((ext_vector_type(8)));

__device__ __forceinline__ int imin(int a, int b) { return a < b ? a : b; }

#define GLOAD_LDS16(g, l)                                                      \
    __builtin_amdgcn_global_load_lds(                                          \
        (const __attribute__((address_space(1))) unsigned int*)(g),            \
        (__attribute__((address_space(3))) unsigned int*)(l), 16, 0, 0)

// ---------------------------------------------------------------------------
// Kernel 0: wv (fp32) -> interleaved f16 workspace.
// ws16 layout per node n (512 f16 = 1KB): [0,256) = wv16 row, [256,512) = pj16
// row (written later by proj_gemm). One contiguous 1KB region per node so the
// att gather of (k,v) for one neighbor touches one line run, not two arrays.
// ---------------------------------------------------------------------------
__global__ __launch_bounds__(256) void prep_f16(const float* __restrict__ wv,
                                                _Float16* __restrict__ ws16) {
    const int stride = gridDim.x * blockDim.x;
    const int total = N_NODES * 32;  // chunks of 8 f32
    for (int i = blockIdx.x * blockDim.x + threadIdx.x; i < total; i += stride) {
        const size_t e = (size_t)i * 8;
        const size_t n = e >> 8, c = e & 255;
        f32x4 a = *(const f32x4*)&wv[e];
        f32x4 b = *(const f32x4*)&wv[e + 4];
        h16x8 h = {(_Float16)a[0], (_Float16)a[1], (_Float16)a[2], (_Float16)a[3],
                   (_Float16)b[0], (_Float16)b[1], (_Float16)b[2], (_Float16)b[3]};
        *(h16x8*)&ws16[n * 512 + c] = h;
    }
}

// ---------------------------------------------------------------------------
// Kernel 1: proj = leaky_relu(word_vec @ W1^T) -> out (fp32) + pj16 half of ws.
// BM=64, BN=256 (full), BK=64. 4 waves; wave w owns all 64 rows x cols [64w,64w+64).
// W1 lives in registers: bq[4][8] h16x8 = 128 VGPR, loaded once from fp32 W1.
// A staged from f16 ws via global_load_lds(16B), double-buffered, source-address
// pre-swizzle so ds_read_b128 is bank-conflict-free.
// ---------------------------------------------------------------------------
__global__ __launch_bounds__(256, 2) void proj_gemm(const _Float16* __restrict__ ws16,
                                                    const float* __restrict__ W,
                                                    float* __restrict__ out,
                                                    _Float16* __restrict__ pjdst) {
    __shared__ _Float16 As[2][64 * 64];  // 2 x 8 KiB, row stride 128B, swizzled

    const int m0 = blockIdx.x * 64;
    const int t = threadIdx.x;
    const int lane = t & 63;
    const int w = t >> 6;
    const int wn = w * 64;

    // ---- stage(kk=0, buf 0): wave w stages rows w*16 .. w*16+15 ----
    const int chs = ((lane & 7) ^ (lane >> 3)) * 16;  // swizzled source chunk byte
    {
#pragma unroll
        for (int i = 0; i < 2; ++i) {
            const int r0 = w * 16 + i * 8;
            const int grow = imin(m0 + r0 + (lane >> 3), N_NODES - 1);
            const char* g = (const char*)ws16 + (size_t)grow * 1024 + chs;
            GLOAD_LDS16(g, (char*)&As[0][0] + r0 * 128);
        }
    }

    // ---- load all B fragments (W1, fp32 -> f16 in regs) ----
    h16x8 bq[4][8];
#pragma unroll
    for (int ni = 0; ni < 4; ++ni) {
#pragma unroll
        for (int ks = 0; ks < 8; ++ks) {
            const int nrow = wn + ni * 16 + (lane & 15);
            const int kb = ks * 32 + (lane >> 4) * 8;
            f32x4 v0 = *(const f32x4*)&W[(size_t)nrow * 256 + kb];
            f32x4 v1 = *(const f32x4*)&W[(size_t)nrow * 256 + kb + 4];
            bq[ni][ks] = h16x8{(_Float16)v0[0], (_Float16)v0[1], (_Float16)v0[2],
                               (_Float16)v0[3], (_Float16)v1[0], (_Float16)v1[1],
                               (_Float16)v1[2], (_Float16)v1[3]};
        }
    }

    f32x4 acc[4][4];
#pragma unroll
    for (int i = 0; i < 4; ++i)
#pragma unroll
        for (int j = 0; j < 4; ++j) acc[i][j] = f32x4{0.f, 0.f, 0.f, 0.f};

    asm volatile("s_waitcnt vmcnt(0)" ::: "memory");
    __syncthreads();

#pragma unroll
    for (int kk = 0; kk < 4; ++kk) {
        const int cur = kk & 1;
        // prefetch next A K-slice into the other buffer
        if (kk < 3) {
#pragma unroll
            for (int i = 0; i < 2; ++i) {
                const int r0 = w * 16 + i * 8;
                const int grow = imin(m0 + r0 + (lane >> 3), N_NODES - 1);
                const char* g =
                    (const char*)ws16 + (size_t)grow * 1024 + (kk + 1) * 128 + chs;
                GLOAD_LDS16(g, (char*)&As[cur ^ 1][0] + r0 * 128);
            }
        }
        // compute on current buffer: 2 sub-steps of K=32
#pragma unroll
        for (int ksl = 0; ksl < 2; ++ksl) {
            const int colb = ksl * 64 + ((lane >> 4) * 16);
            h16x8 af[4];
#pragma unroll
            for (int mi = 0; mi < 4; ++mi) {
                const int row = mi * 16 + (lane & 15);
                const int byte = row * 128 + (colb ^ ((row & 7) << 4));
                af[mi] = *(const h16x8*)((const char*)&As[cur][0] + byte);
            }
#pragma unroll
            for (int mi = 0; mi < 4; ++mi)
#pragma unroll
                for (int ni = 0; ni < 4; ++ni)
                    acc[mi][ni] = __builtin_amdgcn_mfma_f32_16x16x32_f16(
                        af[mi], bq[ni][kk * 2 + ksl], acc[mi][ni], 0, 0, 0);
        }
        asm volatile("s_waitcnt vmcnt(0)" ::: "memory");
        __syncthreads();
    }

    // ---- epilogue: leaky_relu + fp32 out + f16 pj16 half ----
    const int cr = (lane >> 4) * 4;
    const int cc = lane & 15;
#pragma unroll
    for (int mi = 0; mi < 4; ++mi) {
#pragma unroll
        for (int r = 0; r < 4; ++r) {
            const int grow = m0 + mi * 16 + cr + r;
            if (grow < N_NODES) {
#pragma unroll
                for (int ni = 0; ni < 4; ++ni) {
                    float v = acc[mi][ni][r];
                    v = v > 0.f ? v : 0.2f * v;
                    const int col = wn + ni * 16 + cc;
                    out[(size_t)grow * 256 + col] = v;
                    pjdst[(size_t)grow * 512 + 256 + col] = (_Float16)v;
                }
            }
        }
    }
}

// ---------------------------------------------------------------------------
// Kernel 2: scores + masked dual softmax + weighted aggregation, fused scatter.
// One block / b; wave w owns neighbors 8w..8w+7. All gathers from interleaved
// f16 ws (1KB per node). Writes agg directly to out[src].
// ---------------------------------------------------------------------------
__global__ __launch_bounds__(256) void att_agg16(const _Float16* __restrict__ ws16,
                                                 const float* __restrict__ Waux,
                                                 const float* __restrict__ aux,
                                                 const int* __restrict__ src_idx,
                                                 const int* __restrict__ nidx,
                                                 const int* __restrict__ smask,
                                                 float* __restrict__ out) {
    __shared__ int   nsh[32];
    __shared__ int   msh[32];
    __shared__ float sc[32];
    __shared__ float sa[32];
    __shared__ float wsh[32];
    __shared__ float part[4][64][4];

    const int b = blockIdx.x;
    const int t = threadIdx.x;
    const int lane = t & 63;
    const int w = t >> 6;
    const int src = src_idx[b];

    if (t < 32) {
        nsh[t] = nidx[b * KN + t];
        msh[t] = smask[b * KN + t];
        f32x4 a4 = *(const f32x4*)&aux[((size_t)b * KN + t) * 4];
        const float x = a4[0] * Waux[0] + a4[1] * Waux[1] + a4[2] * Waux[2] + a4[3] * Waux[3];
        sa[t] = 1.f / (1.f + expf(-x));
    }
    const h16x4 qh = *(const h16x4*)&ws16[(size_t)src * 512 + lane * 4];
    const float q0 = (float)qh[0], q1 = (float)qh[1], q2 = (float)qh[2], q3 = (float)qh[3];
    __syncthreads();

    int nk[8];
#pragma unroll
    for (int i = 0; i < 8; ++i) nk[i] = nsh[w * 8 + i];

    // preload 8 k rows + 8 v rows (8B/lane each; k and v adjacent in memory)
    h16x4 k4[8], v4[8];
#pragma unroll
    for (int i = 0; i < 8; ++i)
        k4[i] = *(const h16x4*)&ws16[(size_t)nk[i] * 512 + lane * 4];
#pragma unroll
    for (int i = 0; i < 8; ++i)
        v4[i] = *(const h16x4*)&ws16[(size_t)nk[i] * 512 + 256 + lane * 4];

    // scores: full-wave 256-dim dots
#pragma unroll
    for (int i = 0; i < 8; ++i) {
        float p = q0 * (float)k4[i][0] + q1 * (float)k4[i][1] + q2 * (float)k4[i][2] +
                  q3 * (float)k4[i][3];
#pragma unroll
        for (int o = 32; o > 0; o >>= 1) p += __shfl_xor(p, o);
        if (lane == 0) sc[w * 8 + i] = 5.f * p;
    }
    __syncthreads();

    // masked dual softmax over K=32 (lanes 0..31 of wave 0)
    if (t < 32) {
        const bool mk = (msh[t] == 1);
        const float s1 = mk ? sc[t] : NEGV;
        const float s2 = mk ? sa[t] : NEGV;
        float m1 = s1, m2 = s2;
#pragma unroll
        for (int o = 16; o > 0; o >>= 1) {
            m1 = fmaxf(m1, __shfl_xor(m1, o));
            m2 = fmaxf(m2, __shfl_xor(m2, o));
        }
        const float e1 = expf(s1 - m1), e2 = expf(s2 - m2);
        float z1 = e1, z2 = e2;
#pragma unroll
        for (int o = 16; o > 0; o >>= 1) {
            z1 += __shfl_xor(z1, o);
            z2 += __shfl_xor(z2, o);
        }
        wsh[t] = 0.5f * (e1 / z1 + e2 / z2);
    }
    __syncthreads();

    // weighted partial sum (v4 already in regs)
    f32x4 pacc = f32x4{0.f, 0.f, 0.f, 0.f};
#pragma unroll
    for (int i = 0; i < 8; ++i) {
        const float wk = wsh[w * 8 + i];
#pragma unroll
        for (int j = 0; j < 4; ++j) pacc[j] += wk * (float)v4[i][j];
    }
    *(f32x4*)&part[w][lane][0] = pacc;
    __syncthreads();

    if (w == 0) {
        f32x4 s0 = *(const f32x4*)&part[0][lane][0];
        f32x4 s1 = *(const f32x4*)&part[1][lane][0];
        f32x4 s2 = *(const f32x4*)&part[2][lane][0];
        f32x4 s3 = *(const f32x4*)&part[3][lane][0];
        f32x4 s;
#pragma unroll
        for (int j = 0; j < 4; ++j) s[j] = (s0[j] + s1[j]) + (s2[j] + s3[j]);
        *(f32x4*)&out[(size_t)src * 256 + lane * 4] = s;  // fused scatter
    }
}

extern "C" void kernel_launch(void* const* d_in, const int* in_sizes, int n_in,
                              void* d_out, int out_size, void* d_ws, size_t ws_size,
                              hipStream_t stream) {
    const float* wv   = (const float*)d_in[0];  // word_vec [N,256]
    const float* W1   = (const float*)d_in[1];  // [256,256]
    const float* Waux = (const float*)d_in[2];  // [1,4]
    const float* aux  = (const float*)d_in[3];  // [B,K,4]
    const int*   src  = (const int*)d_in[4];    // [B]
    const int*   nidx = (const int*)d_in[5];    // [B,K]
    const int*   smk  = (const int*)d_in[6];    // [B,K]
    float* out = (float*)d_out;                 // [N,256]
    _Float16* ws16 = (_Float16*)d_ws;           // [N,512] interleaved (102.4 MB,
                                                // proven to fit in round 6)

    prep_f16<<<dim3(4096), dim3(256), 0, stream>>>(wv, ws16);
    proj_gemm<<<dim3((N_NODES + 63) / 64), dim3(256), 0, stream>>>(ws16, W1, out, ws16);
    att_agg16<<<dim3(BQ), dim3(256), 0, stream>>>(ws16, Waux, aux, src, nidx, smk, out);
}

// Round 10
// 360.982 us; speedup vs baseline: 1.2484x; 1.0052x over previous
//
#include <hip/hip_runtime.h>
#include <cstdint>

#define N_NODES 100000
#define BQ      20000
#define KN      32
#define NEGV    -1000000.0f

typedef float    f32x4 __attribute__((ext_vector_type(4)));
typedef _Float16 h16x4 __attribute__((ext_vector_type(4)));
typedef _Float16 h16x8 __attribute__((ext_vector_type(8)));

__device__ __forceinline__ int imin(int a, int b) { return a < b ? a : b; }

#define GLOAD_LDS16(g, l)                                                      \
    __builtin_amdgcn_global_load_lds(                                          \
        (const __attribute__((address_space(1))) unsigned int*)(g),            \
        (__attribute__((address_space(3))) unsigned int*)(l), 16, 0, 0)

// ---------------------------------------------------------------------------
// Kernel 0: wv (fp32) -> interleaved f16 workspace.
// ws16 layout per node n (512 f16 = 1KB): [0,256) = wv16 row, [256,512) = pj16
// row (written later by proj_gemm). wv reads are non-temporal (read-once);
// ws16 writes stay cached (hot set for proj + att).
// ---------------------------------------------------------------------------
__global__ __launch_bounds__(256) void prep_f16(const float* __restrict__ wv,
                                                _Float16* __restrict__ ws16) {
    const int stride = gridDim.x * blockDim.x;
    const int total = N_NODES * 32;  // chunks of 8 f32
    for (int i = blockIdx.x * blockDim.x + threadIdx.x; i < total; i += stride) {
        const size_t e = (size_t)i * 8;
        const size_t n = e >> 8, c = e & 255;
        f32x4 a = __builtin_nontemporal_load((const f32x4*)&wv[e]);
        f32x4 b = __builtin_nontemporal_load((const f32x4*)&wv[e + 4]);
        h16x8 h = {(_Float16)a[0], (_Float16)a[1], (_Float16)a[2], (_Float16)a[3],
                   (_Float16)b[0], (_Float16)b[1], (_Float16)b[2], (_Float16)b[3]};
        *(h16x8*)&ws16[n * 512 + c] = h;
    }
}

// ---------------------------------------------------------------------------
// Kernel 1: proj = leaky_relu(word_vec @ W1^T) -> out (fp32, NT stores) +
// pj16 half of ws (cached stores). BM=64, BN=256, BK=64; W1 in registers;
// A staged from f16 ws via global_load_lds(16B), double-buffered, swizzled.
// ---------------------------------------------------------------------------
__global__ __launch_bounds__(256, 2) void proj_gemm(const _Float16* __restrict__ ws16,
                                                    const float* __restrict__ W,
                                                    float* __restrict__ out,
                                                    _Float16* __restrict__ pjdst) {
    __shared__ _Float16 As[2][64 * 64];  // 2 x 8 KiB, row stride 128B, swizzled

    const int m0 = blockIdx.x * 64;
    const int t = threadIdx.x;
    const int lane = t & 63;
    const int w = t >> 6;
    const int wn = w * 64;

    // ---- stage(kk=0, buf 0): wave w stages rows w*16 .. w*16+15 ----
    const int chs = ((lane & 7) ^ (lane >> 3)) * 16;  // swizzled source chunk byte
    {
#pragma unroll
        for (int i = 0; i < 2; ++i) {
            const int r0 = w * 16 + i * 8;
            const int grow = imin(m0 + r0 + (lane >> 3), N_NODES - 1);
            const char* g = (const char*)ws16 + (size_t)grow * 1024 + chs;
            GLOAD_LDS16(g, (char*)&As[0][0] + r0 * 128);
        }
    }

    // ---- load all B fragments (W1, fp32 -> f16 in regs) ----
    h16x8 bq[4][8];
#pragma unroll
    for (int ni = 0; ni < 4; ++ni) {
#pragma unroll
        for (int ks = 0; ks < 8; ++ks) {
            const int nrow = wn + ni * 16 + (lane & 15);
            const int kb = ks * 32 + (lane >> 4) * 8;
            f32x4 v0 = *(const f32x4*)&W[(size_t)nrow * 256 + kb];
            f32x4 v1 = *(const f32x4*)&W[(size_t)nrow * 256 + kb + 4];
            bq[ni][ks] = h16x8{(_Float16)v0[0], (_Float16)v0[1], (_Float16)v0[2],
                               (_Float16)v0[3], (_Float16)v1[0], (_Float16)v1[1],
                               (_Float16)v1[2], (_Float16)v1[3]};
        }
    }

    f32x4 acc[4][4];
#pragma unroll
    for (int i = 0; i < 4; ++i)
#pragma unroll
        for (int j = 0; j < 4; ++j) acc[i][j] = f32x4{0.f, 0.f, 0.f, 0.f};

    asm volatile("s_waitcnt vmcnt(0)" ::: "memory");
    __syncthreads();

#pragma unroll
    for (int kk = 0; kk < 4; ++kk) {
        const int cur = kk & 1;
        // prefetch next A K-slice into the other buffer
        if (kk < 3) {
#pragma unroll
            for (int i = 0; i < 2; ++i) {
                const int r0 = w * 16 + i * 8;
                const int grow = imin(m0 + r0 + (lane >> 3), N_NODES - 1);
                const char* g =
                    (const char*)ws16 + (size_t)grow * 1024 + (kk + 1) * 128 + chs;
                GLOAD_LDS16(g, (char*)&As[cur ^ 1][0] + r0 * 128);
            }
        }
        // compute on current buffer: 2 sub-steps of K=32
#pragma unroll
        for (int ksl = 0; ksl < 2; ++ksl) {
            const int colb = ksl * 64 + ((lane >> 4) * 16);
            h16x8 af[4];
#pragma unroll
            for (int mi = 0; mi < 4; ++mi) {
                const int row = mi * 16 + (lane & 15);
                const int byte = row * 128 + (colb ^ ((row & 7) << 4));
                af[mi] = *(const h16x8*)((const char*)&As[cur][0] + byte);
            }
#pragma unroll
            for (int mi = 0; mi < 4; ++mi)
#pragma unroll
                for (int ni = 0; ni < 4; ++ni)
                    acc[mi][ni] = __builtin_amdgcn_mfma_f32_16x16x32_f16(
                        af[mi], bq[ni][kk * 2 + ksl], acc[mi][ni], 0, 0, 0);
        }
        asm volatile("s_waitcnt vmcnt(0)" ::: "memory");
        __syncthreads();
    }

    // ---- epilogue: leaky_relu + fp32 out (NT) + f16 pj16 half (cached) ----
    const int cr = (lane >> 4) * 4;
    const int cc = lane & 15;
#pragma unroll
    for (int mi = 0; mi < 4; ++mi) {
#pragma unroll
        for (int r = 0; r < 4; ++r) {
            const int grow = m0 + mi * 16 + cr + r;
            if (grow < N_NODES) {
#pragma unroll
                for (int ni = 0; ni < 4; ++ni) {
                    float v = acc[mi][ni][r];
                    v = v > 0.f ? v : 0.2f * v;
                    const int col = wn + ni * 16 + cc;
                    __builtin_nontemporal_store(v, &out[(size_t)grow * 256 + col]);
                    pjdst[(size_t)grow * 512 + 256 + col] = (_Float16)v;
                }
            }
        }
    }
}

// ---------------------------------------------------------------------------
// Kernel 2: scores + masked dual softmax + weighted aggregation, fused scatter.
// One block / b; wave w owns neighbors 8w..8w+7. Gathers from interleaved f16
// ws (cached; 6.4x average reuse). aux read + agg store are non-temporal.
// ---------------------------------------------------------------------------
__global__ __launch_bounds__(256) void att_agg16(const _Float16* __restrict__ ws16,
                                                 const float* __restrict__ Waux,
                                                 const float* __restrict__ aux,
                                                 const int* __restrict__ src_idx,
                                                 const int* __restrict__ nidx,
                                                 const int* __restrict__ smask,
                                                 float* __restrict__ out) {
    __shared__ int   nsh[32];
    __shared__ int   msh[32];
    __shared__ float sc[32];
    __shared__ float sa[32];
    __shared__ float wsh[32];
    __shared__ float part[4][64][4];

    const int b = blockIdx.x;
    const int t = threadIdx.x;
    const int lane = t & 63;
    const int w = t >> 6;
    const int src = src_idx[b];

    if (t < 32) {
        nsh[t] = nidx[b * KN + t];
        msh[t] = smask[b * KN + t];
        f32x4 a4 = __builtin_nontemporal_load((const f32x4*)&aux[((size_t)b * KN + t) * 4]);
        const float x = a4[0] * Waux[0] + a4[1] * Waux[1] + a4[2] * Waux[2] + a4[3] * Waux[3];
        sa[t] = 1.f / (1.f + expf(-x));
    }
    const h16x4 qh = *(const h16x4*)&ws16[(size_t)src * 512 + lane * 4];
    const float q0 = (float)qh[0], q1 = (float)qh[1], q2 = (float)qh[2], q3 = (float)qh[3];
    __syncthreads();

    int nk[8];
#pragma unroll
    for (int i = 0; i < 8; ++i) nk[i] = nsh[w * 8 + i];

    // preload 8 k rows + 8 v rows (8B/lane each; k and v adjacent in memory)
    h16x4 k4[8], v4[8];
#pragma unroll
    for (int i = 0; i < 8; ++i)
        k4[i] = *(const h16x4*)&ws16[(size_t)nk[i] * 512 + lane * 4];
#pragma unroll
    for (int i = 0; i < 8; ++i)
        v4[i] = *(const h16x4*)&ws16[(size_t)nk[i] * 512 + 256 + lane * 4];

    // scores: full-wave 256-dim dots
#pragma unroll
    for (int i = 0; i < 8; ++i) {
        float p = q0 * (float)k4[i][0] + q1 * (float)k4[i][1] + q2 * (float)k4[i][2] +
                  q3 * (float)k4[i][3];
#pragma unroll
        for (int o = 32; o > 0; o >>= 1) p += __shfl_xor(p, o);
        if (lane == 0) sc[w * 8 + i] = 5.f * p;
    }
    __syncthreads();

    // masked dual softmax over K=32 (lanes 0..31 of wave 0)
    if (t < 32) {
        const bool mk = (msh[t] == 1);
        const float s1 = mk ? sc[t] : NEGV;
        const float s2 = mk ? sa[t] : NEGV;
        float m1 = s1, m2 = s2;
#pragma unroll
        for (int o = 16; o > 0; o >>= 1) {
            m1 = fmaxf(m1, __shfl_xor(m1, o));
            m2 = fmaxf(m2, __shfl_xor(m2, o));
        }
        const float e1 = expf(s1 - m1), e2 = expf(s2 - m2);
        float z1 = e1, z2 = e2;
#pragma unroll
        for (int o = 16; o > 0; o >>= 1) {
            z1 += __shfl_xor(z1, o);
            z2 += __shfl_xor(z2, o);
        }
        wsh[t] = 0.5f * (e1 / z1 + e2 / z2);
    }
    __syncthreads();

    // weighted partial sum (v4 already in regs)
    f32x4 pacc = f32x4{0.f, 0.f, 0.f, 0.f};
#pragma unroll
    for (int i = 0; i < 8; ++i) {
        const float wk = wsh[w * 8 + i];
#pragma unroll
        for (int j = 0; j < 4; ++j) pacc[j] += wk * (float)v4[i][j];
    }
    *(f32x4*)&part[w][lane][0] = pacc;
    __syncthreads();

    if (w == 0) {
        f32x4 s0 = *(const f32x4*)&part[0][lane][0];
        f32x4 s1 = *(const f32x4*)&part[1][lane][0];
        f32x4 s2 = *(const f32x4*)&part[2][lane][0];
        f32x4 s3 = *(const f32x4*)&part[3][lane][0];
        f32x4 s;
#pragma unroll
        for (int j = 0; j < 4; ++j) s[j] = (s0[j] + s1[j]) + (s2[j] + s3[j]);
        __builtin_nontemporal_store(s, (f32x4*)&out[(size_t)src * 256 + lane * 4]);
    }
}

extern "C" void kernel_launch(void* const* d_in, const int* in_sizes, int n_in,
                              void* d_out, int out_size, void* d_ws, size_t ws_size,
                              hipStream_t stream) {
    const float* wv   = (const float*)d_in[0];  // word_vec [N,256]
    const float* W1   = (const float*)d_in[1];  // [256,256]
    const float* Waux = (const float*)d_in[2];  // [1,4]
    const float* aux  = (const float*)d_in[3];  // [B,K,4]
    const int*   src  = (const int*)d_in[4];    // [B]
    const int*   nidx = (const int*)d_in[5];    // [B,K]
    const int*   smk  = (const int*)d_in[6];    // [B,K]
    float* out = (float*)d_out;                 // [N,256]
    _Float16* ws16 = (_Float16*)d_ws;           // [N,512] interleaved (102.4 MB)

    prep_f16<<<dim3(4096), dim3(256), 0, stream>>>(wv, ws16);
    proj_gemm<<<dim3((N_NODES + 63) / 64), dim3(256), 0, stream>>>(ws16, W1, out, ws16);
    att_agg16<<<dim3(BQ), dim3(256), 0, stream>>>(ws16, Waux, aux, src, nidx, smk, out);
}